// Round 1
// baseline (5544.831 us; speedup 1.0000x reference)
//
#include <hip/hip_runtime.h>

#define DD 128  // emb dim, fixed by problem

// K1: g1 = dropout(emb, u1); h1 = 0   (vectorized over float4)
__global__ __launch_bounds__(256) void k_drop1(const float* __restrict__ emb,
                                               const float* __restrict__ u1,
                                               float* __restrict__ g1,
                                               float* __restrict__ h1,
                                               int total4) {
    int i = blockIdx.x * 256 + threadIdx.x;
    if (i >= total4) return;
    float4 h = ((const float4*)emb)[i];
    float4 u = ((const float4*)u1)[i];
    const float s = 1.0f / 0.9f;
    float4 g;
    g.x = (u.x >= 0.1f) ? h.x * s : 0.0f;
    g.y = (u.y >= 0.1f) ? h.y * s : 0.0f;
    g.z = (u.z >= 0.1f) ? h.z * s : 0.0f;
    g.w = (u.w >= 0.1f) ? h.w * s : 0.0f;
    ((float4*)g1)[i] = g;
    ((float4*)h1)[i] = make_float4(0.0f, 0.0f, 0.0f, 0.0f);
}

// K3: g2 = dropout(h1, u2); out = (emb + h1) / 3
__global__ __launch_bounds__(256) void k_drop2(const float* __restrict__ emb,
                                               const float* __restrict__ h1,
                                               const float* __restrict__ u2,
                                               float* __restrict__ g2,
                                               float* __restrict__ out,
                                               int total4) {
    int i = blockIdx.x * 256 + threadIdx.x;
    if (i >= total4) return;
    float4 h = ((const float4*)h1)[i];
    float4 u = ((const float4*)u2)[i];
    float4 e = ((const float4*)emb)[i];
    const float s = 1.0f / 0.9f;
    float4 g;
    g.x = (u.x >= 0.1f) ? h.x * s : 0.0f;
    g.y = (u.y >= 0.1f) ? h.y * s : 0.0f;
    g.z = (u.z >= 0.1f) ? h.z * s : 0.0f;
    g.w = (u.w >= 0.1f) ? h.w * s : 0.0f;
    ((float4*)g2)[i] = g;
    const float t = 1.0f / 3.0f;
    float4 o;
    o.x = (e.x + h.x) * t;
    o.y = (e.y + h.y) * t;
    o.z = (e.z + h.z) * t;
    o.w = (e.w + h.w) * t;
    ((float4*)out)[i] = o;
}

// SpMM scatter: dst[rows[e]] += scale * vals[e] * src[cols[e]]
// 32 lanes per edge (float4 each), 8 edges per 256-thread block.
__global__ __launch_bounds__(256) void k_spmm(const int* __restrict__ rows,
                                              const int* __restrict__ cols,
                                              const float* __restrict__ vals,
                                              const float* __restrict__ src,
                                              float* __restrict__ dst,
                                              int E, float scale) {
    int t = blockIdx.x * 256 + threadIdx.x;
    int e = t >> 5;
    int lane = t & 31;
    if (e >= E) return;
    int r = rows[e];
    int c = cols[e];
    float v = vals[e] * scale;
    float4 g = ((const float4*)(src + (size_t)c * DD))[lane];
    float* p = dst + (size_t)r * DD + lane * 4;
    atomicAdd(p + 0, v * g.x);
    atomicAdd(p + 1, v * g.y);
    atomicAdd(p + 2, v * g.z);
    atomicAdd(p + 3, v * g.w);
}

extern "C" void kernel_launch(void* const* d_in, const int* in_sizes, int n_in,
                              void* d_out, int out_size, void* d_ws, size_t ws_size,
                              hipStream_t stream) {
    // inputs: x[N], rows[E], cols[E], A_vals[E], emb[N*D], u1[N*D], u2[N*D]
    const int* rows = (const int*)d_in[1];
    const int* cols = (const int*)d_in[2];
    const float* vals = (const float*)d_in[3];
    const float* emb = (const float*)d_in[4];
    const float* u1 = (const float*)d_in[5];
    const float* u2 = (const float*)d_in[6];
    float* out = (float*)d_out;

    const int N = in_sizes[0];
    const int E = in_sizes[1];
    const size_t ND = (size_t)N * DD;

    float* g1 = (float*)d_ws;          // buf0: g1, later reused as g2
    float* h1 = (float*)d_ws + ND;     // buf1: h1 accumulator

    const int total4 = (int)(ND / 4);
    const int gridElem = (total4 + 255) / 256;
    const int gridEdge = (int)(((size_t)E * 32 + 255) / 256);

    // 1) g1 = dropout(emb, u1); h1 = 0
    k_drop1<<<gridElem, 256, 0, stream>>>(emb, u1, g1, h1, total4);
    // 2) h1 += A * g1
    k_spmm<<<gridEdge, 256, 0, stream>>>(rows, cols, vals, g1, h1, E, 1.0f);
    // 3) g2 = dropout(h1, u2); out = (emb + h1)/3
    k_drop2<<<gridElem, 256, 0, stream>>>(emb, h1, u2, g1, out, total4);
    // 4) out += (A * g2)/3
    k_spmm<<<gridEdge, 256, 0, stream>>>(rows, cols, vals, g1, out, E, 1.0f / 3.0f);
}

// Round 2
// 628.684 us; speedup vs baseline: 8.8197x; 8.8197x over previous
//
#include <hip/hip_runtime.h>

#define DD 128            // emb dim, fixed by problem
#define SCAN_CHUNK 1024   // elements per scan1 block

// ---- CSR build ----------------------------------------------------------

__global__ __launch_bounds__(256) void k_zero(int* __restrict__ p, int n) {
    int i = blockIdx.x * 256 + threadIdx.x;
    if (i < n) p[i] = 0;
}

__global__ __launch_bounds__(256) void k_hist(const int* __restrict__ rows,
                                              int* __restrict__ cnt, int E) {
    int e = blockIdx.x * 256 + threadIdx.x;
    if (e < E) atomicAdd(&cnt[rows[e]], 1);
}

// per-block exclusive scan of 1024 elements (4/thread), block totals -> bsum
__global__ __launch_bounds__(256) void k_scan1(int* __restrict__ data,
                                               int* __restrict__ bsum, int n) {
    __shared__ int s[256];
    int tid = threadIdx.x;
    int base = blockIdx.x * SCAN_CHUNK + tid * 4;
    int v0 = 0, v1 = 0, v2 = 0, v3 = 0;
    if (base + 0 < n) v0 = data[base + 0];
    if (base + 1 < n) v1 = data[base + 1];
    if (base + 2 < n) v2 = data[base + 2];
    if (base + 3 < n) v3 = data[base + 3];
    int tsum = v0 + v1 + v2 + v3;
    s[tid] = tsum;
    __syncthreads();
    for (int off = 1; off < 256; off <<= 1) {
        int t = (tid >= off) ? s[tid - off] : 0;
        __syncthreads();
        s[tid] += t;
        __syncthreads();
    }
    int excl = s[tid] - tsum;           // exclusive prefix of this thread's chunk
    if (tid == 255) bsum[blockIdx.x] = s[255];
    if (base + 0 < n) data[base + 0] = excl;
    if (base + 1 < n) data[base + 1] = excl + v0;
    if (base + 2 < n) data[base + 2] = excl + v0 + v1;
    if (base + 3 < n) data[base + 3] = excl + v0 + v1 + v2;
}

// exclusive scan of block sums (nb <= 1024), single block
__global__ __launch_bounds__(1024) void k_scan2(int* __restrict__ bsum, int nb) {
    __shared__ int s[1024];
    int tid = threadIdx.x;
    if (tid < nb) s[tid] = bsum[tid];
    __syncthreads();
    if (tid == 0) {
        int run = 0;
        for (int i = 0; i < nb; ++i) { int t = s[i]; s[i] = run; run += t; }
    }
    __syncthreads();
    if (tid < nb) bsum[tid] = s[tid];
}

__global__ __launch_bounds__(256) void k_scan3(int* __restrict__ data,
                                               const int* __restrict__ bsum, int n) {
    int i = blockIdx.x * 256 + threadIdx.x;
    if (i < n) data[i] += bsum[i >> 10];
}

// scatter edges into CSR order; rowptr[r] mutates start(r) -> end(r)
__global__ __launch_bounds__(256) void k_scatter(const int* __restrict__ rows,
                                                 const int* __restrict__ cols,
                                                 const float* __restrict__ vals,
                                                 int* __restrict__ rowptr,
                                                 int* __restrict__ cols_s,
                                                 float* __restrict__ vals_s, int E) {
    int e = blockIdx.x * 256 + threadIdx.x;
    if (e >= E) return;
    int r = rows[e];
    int pos = atomicAdd(&rowptr[r], 1);
    cols_s[pos] = cols[e];
    vals_s[pos] = vals[e];
}

// ---- dense ops ----------------------------------------------------------

// g = dropout(src, u)
__global__ __launch_bounds__(256) void k_drop(const float* __restrict__ src,
                                              const float* __restrict__ u,
                                              float* __restrict__ g, int total4) {
    int i = blockIdx.x * 256 + threadIdx.x;
    if (i >= total4) return;
    float4 h = ((const float4*)src)[i];
    float4 uu = ((const float4*)u)[i];
    const float s = 1.0f / 0.9f;
    float4 o;
    o.x = (uu.x >= 0.1f) ? h.x * s : 0.0f;
    o.y = (uu.y >= 0.1f) ? h.y * s : 0.0f;
    o.z = (uu.z >= 0.1f) ? h.z * s : 0.0f;
    o.w = (uu.w >= 0.1f) ? h.w * s : 0.0f;
    ((float4*)g)[i] = o;
}

// gather SpMM: dst[row] = sum_e val*src[col]   (FUSE: dst = (emb+h1+sum)/3)
// 32 lanes per row, float4 per lane; after k_scatter, row range is
// [rowptr[row-1], rowptr[row]) with rowptr[-1] == 0.
template <bool FUSE>
__global__ __launch_bounds__(256) void k_gather(const int* __restrict__ rowptr,
                                                const int* __restrict__ cols_s,
                                                const float* __restrict__ vals_s,
                                                const float* __restrict__ src,
                                                const float* __restrict__ emb,
                                                const float* __restrict__ h1,
                                                float* __restrict__ dst, int N) {
    int t = blockIdx.x * 256 + threadIdx.x;
    int row = t >> 5;
    int lane = t & 31;
    if (row >= N) return;
    int start = (row == 0) ? 0 : rowptr[row - 1];
    int end = rowptr[row];
    float ax = 0.f, ay = 0.f, az = 0.f, aw = 0.f;
    for (int e = start; e < end; ++e) {
        float v = vals_s[e];
        int c = cols_s[e];
        float4 g = ((const float4*)(src + ((size_t)c << 7)))[lane];
        ax = fmaf(v, g.x, ax);
        ay = fmaf(v, g.y, ay);
        az = fmaf(v, g.z, az);
        aw = fmaf(v, g.w, aw);
    }
    size_t o = ((size_t)row << 7) + (size_t)lane * 4;
    if (FUSE) {
        float4 e4 = *(const float4*)(emb + o);
        float4 h4 = *(const float4*)(h1 + o);
        const float t3 = 1.0f / 3.0f;
        float4 r;
        r.x = (e4.x + h4.x + ax) * t3;
        r.y = (e4.y + h4.y + ay) * t3;
        r.z = (e4.z + h4.z + az) * t3;
        r.w = (e4.w + h4.w + aw) * t3;
        *(float4*)(dst + o) = r;
    } else {
        *(float4*)(dst + o) = make_float4(ax, ay, az, aw);
    }
}

// ---- launch -------------------------------------------------------------

extern "C" void kernel_launch(void* const* d_in, const int* in_sizes, int n_in,
                              void* d_out, int out_size, void* d_ws, size_t ws_size,
                              hipStream_t stream) {
    // inputs: x[N], rows[E], cols[E], A_vals[E], emb[N*D], u1[N*D], u2[N*D]
    const int* rows = (const int*)d_in[1];
    const int* cols = (const int*)d_in[2];
    const float* vals = (const float*)d_in[3];
    const float* emb = (const float*)d_in[4];
    const float* u1 = (const float*)d_in[5];
    const float* u2 = (const float*)d_in[6];
    float* out = (float*)d_out;

    const int N = in_sizes[0];
    const int E = in_sizes[1];
    const size_t ND = (size_t)N * DD;

    // workspace layout
    char* ws = (char*)d_ws;
    float* g      = (float*)ws;                 ws += ND * sizeof(float); // 51.2MB
    float* h1     = (float*)ws;                 ws += ND * sizeof(float); // 51.2MB
    int*   rowptr = (int*)ws;                   ws += (size_t)N * sizeof(int);
    int*   cols_s = (int*)ws;                   ws += (size_t)E * sizeof(int);
    float* vals_s = (float*)ws;                 ws += (size_t)E * sizeof(float);
    int*   bsum   = (int*)ws;                   // up to 1024 ints

    const int total4 = (int)(ND / 4);
    const int gridElem = (total4 + 255) / 256;
    const int gridE = (E + 255) / 256;
    const int gridN = (N + 255) / 256;
    const int nScanBlocks = (N + SCAN_CHUNK - 1) / SCAN_CHUNK;
    const int gridRow = (N * 32 + 255) / 256;   // 8 rows per block

    // CSR build
    k_zero<<<gridN, 256, 0, stream>>>(rowptr, N);
    k_hist<<<gridE, 256, 0, stream>>>(rows, rowptr, E);
    k_scan1<<<nScanBlocks, 256, 0, stream>>>(rowptr, bsum, N);
    k_scan2<<<1, 1024, 0, stream>>>(bsum, nScanBlocks);
    k_scan3<<<gridN, 256, 0, stream>>>(rowptr, bsum, N);
    k_scatter<<<gridE, 256, 0, stream>>>(rows, cols, vals, rowptr, cols_s, vals_s, E);

    // layer 1: g = dropout(emb,u1); h1 = A*g
    k_drop<<<gridElem, 256, 0, stream>>>(emb, u1, g, total4);
    k_gather<false><<<gridRow, 256, 0, stream>>>(rowptr, cols_s, vals_s, g, nullptr, nullptr, h1, N);

    // layer 2: g = dropout(h1,u2); out = (emb + h1 + A*g)/3
    k_drop<<<gridElem, 256, 0, stream>>>(h1, u2, g, total4);
    k_gather<true><<<gridRow, 256, 0, stream>>>(rowptr, cols_s, vals_s, g, emb, h1, out, N);
}

// Round 3
// 554.778 us; speedup vs baseline: 9.9947x; 1.1332x over previous
//
#include <hip/hip_runtime.h>

#define DD 128            // emb dim, fixed by problem
#define SCAN_CHUNK 1024   // elements per scan1 block

struct __align__(8) Edge { int c; float v; };

// ---- CSR build ----------------------------------------------------------

__global__ __launch_bounds__(256) void k_zero(int* __restrict__ p, int n) {
    int i = blockIdx.x * 256 + threadIdx.x;
    if (i < n) p[i] = 0;
}

// count rows AND record each edge's rank within its row
__global__ __launch_bounds__(256) void k_hist(const int* __restrict__ rows,
                                              int* __restrict__ cnt,
                                              int* __restrict__ rank, int E) {
    int e = blockIdx.x * 256 + threadIdx.x;
    if (e < E) rank[e] = atomicAdd(&cnt[rows[e]], 1);
}

// per-block exclusive scan of 1024 elements (4/thread), block totals -> bsum
__global__ __launch_bounds__(256) void k_scan1(int* __restrict__ data,
                                               int* __restrict__ bsum, int n) {
    __shared__ int s[256];
    int tid = threadIdx.x;
    int base = blockIdx.x * SCAN_CHUNK + tid * 4;
    int v0 = 0, v1 = 0, v2 = 0, v3 = 0;
    if (base + 0 < n) v0 = data[base + 0];
    if (base + 1 < n) v1 = data[base + 1];
    if (base + 2 < n) v2 = data[base + 2];
    if (base + 3 < n) v3 = data[base + 3];
    int tsum = v0 + v1 + v2 + v3;
    s[tid] = tsum;
    __syncthreads();
    for (int off = 1; off < 256; off <<= 1) {
        int t = (tid >= off) ? s[tid - off] : 0;
        __syncthreads();
        s[tid] += t;
        __syncthreads();
    }
    int excl = s[tid] - tsum;
    if (tid == 255) bsum[blockIdx.x] = s[255];
    if (base + 0 < n) data[base + 0] = excl;
    if (base + 1 < n) data[base + 1] = excl + v0;
    if (base + 2 < n) data[base + 2] = excl + v0 + v1;
    if (base + 3 < n) data[base + 3] = excl + v0 + v1 + v2;
}

__global__ __launch_bounds__(1024) void k_scan2(int* __restrict__ bsum, int nb) {
    __shared__ int s[1024];
    int tid = threadIdx.x;
    if (tid < nb) s[tid] = bsum[tid];
    __syncthreads();
    if (tid == 0) {
        int run = 0;
        for (int i = 0; i < nb; ++i) { int t = s[i]; s[i] = run; run += t; }
    }
    __syncthreads();
    if (tid < nb) bsum[tid] = s[tid];
}

__global__ __launch_bounds__(256) void k_scan3(int* __restrict__ data,
                                               const int* __restrict__ bsum, int n) {
    int i = blockIdx.x * 256 + threadIdx.x;
    if (i < n) data[i] += bsum[i >> 10];
}

// no atomics: pos = rowstart[r] + rank[e]; packed 8B write
__global__ __launch_bounds__(256) void k_scatter(const int* __restrict__ rows,
                                                 const int* __restrict__ cols,
                                                 const float* __restrict__ vals,
                                                 const int* __restrict__ rowstart,
                                                 const int* __restrict__ rank,
                                                 Edge* __restrict__ ev, int E) {
    int e = blockIdx.x * 256 + threadIdx.x;
    if (e >= E) return;
    int r = rows[e];
    Edge ed;
    ed.c = cols[e];
    ed.v = vals[e];
    ev[rowstart[r] + rank[e]] = ed;
}

// ---- dense ops ----------------------------------------------------------

__global__ __launch_bounds__(256) void k_drop(const float* __restrict__ src,
                                              const float* __restrict__ u,
                                              float* __restrict__ g, int total4) {
    int i = blockIdx.x * 256 + threadIdx.x;
    if (i >= total4) return;
    float4 h = ((const float4*)src)[i];
    float4 uu = ((const float4*)u)[i];
    const float s = 1.0f / 0.9f;
    float4 o;
    o.x = (uu.x >= 0.1f) ? h.x * s : 0.0f;
    o.y = (uu.y >= 0.1f) ? h.y * s : 0.0f;
    o.z = (uu.z >= 0.1f) ? h.z * s : 0.0f;
    o.w = (uu.w >= 0.1f) ? h.w * s : 0.0f;
    ((float4*)g)[i] = o;
}

// gather SpMM, 32 lanes/row, unroll x4 for MLP.
// MODE 0: dst = A*src
// MODE 1: dst(h1) = A*src; g2 = dropout(h1, u2)       (fused layer-2 dropout)
// MODE 2: dst(out) = (emb + h1in + A*src) / 3
template <int MODE>
__global__ __launch_bounds__(256) void k_gather(const int* __restrict__ rowstart,
                                                const Edge* __restrict__ ev,
                                                const float* __restrict__ src,
                                                const float* __restrict__ u2,
                                                const float* __restrict__ emb,
                                                const float* __restrict__ h1in,
                                                float* __restrict__ dst,
                                                float* __restrict__ g2,
                                                int N, int E) {
    int t = blockIdx.x * 256 + threadIdx.x;
    int row = t >> 5;
    int lane = t & 31;
    if (row >= N) return;
    int start = rowstart[row];
    int end = (row == N - 1) ? E : rowstart[row + 1];
    const float4* s4 = (const float4*)src;
    float ax = 0.f, ay = 0.f, az = 0.f, aw = 0.f;
    int e = start;
    for (; e + 4 <= end; e += 4) {
        Edge e0 = ev[e + 0];
        Edge e1 = ev[e + 1];
        Edge e2 = ev[e + 2];
        Edge e3 = ev[e + 3];
        float4 a0 = s4[((size_t)e0.c << 5) + lane];
        float4 a1 = s4[((size_t)e1.c << 5) + lane];
        float4 a2 = s4[((size_t)e2.c << 5) + lane];
        float4 a3 = s4[((size_t)e3.c << 5) + lane];
        ax = fmaf(e0.v, a0.x, ax); ay = fmaf(e0.v, a0.y, ay);
        az = fmaf(e0.v, a0.z, az); aw = fmaf(e0.v, a0.w, aw);
        ax = fmaf(e1.v, a1.x, ax); ay = fmaf(e1.v, a1.y, ay);
        az = fmaf(e1.v, a1.z, az); aw = fmaf(e1.v, a1.w, aw);
        ax = fmaf(e2.v, a2.x, ax); ay = fmaf(e2.v, a2.y, ay);
        az = fmaf(e2.v, a2.z, az); aw = fmaf(e2.v, a2.w, aw);
        ax = fmaf(e3.v, a3.x, ax); ay = fmaf(e3.v, a3.y, ay);
        az = fmaf(e3.v, a3.z, az); aw = fmaf(e3.v, a3.w, aw);
    }
    for (; e < end; ++e) {
        Edge ed = ev[e];
        float4 a = s4[((size_t)ed.c << 5) + lane];
        ax = fmaf(ed.v, a.x, ax); ay = fmaf(ed.v, a.y, ay);
        az = fmaf(ed.v, a.z, az); aw = fmaf(ed.v, a.w, aw);
    }
    size_t o = ((size_t)row << 7) + (size_t)lane * 4;
    if (MODE == 0) {
        *(float4*)(dst + o) = make_float4(ax, ay, az, aw);
    } else if (MODE == 1) {
        *(float4*)(dst + o) = make_float4(ax, ay, az, aw);   // h1
        float4 uu = *(const float4*)(u2 + o);
        const float s = 1.0f / 0.9f;
        float4 gg;
        gg.x = (uu.x >= 0.1f) ? ax * s : 0.0f;
        gg.y = (uu.y >= 0.1f) ? ay * s : 0.0f;
        gg.z = (uu.z >= 0.1f) ? az * s : 0.0f;
        gg.w = (uu.w >= 0.1f) ? aw * s : 0.0f;
        *(float4*)(g2 + o) = gg;
    } else {
        float4 e4 = *(const float4*)(emb + o);
        float4 h4 = *(const float4*)(h1in + o);
        const float t3 = 1.0f / 3.0f;
        float4 r;
        r.x = (e4.x + h4.x + ax) * t3;
        r.y = (e4.y + h4.y + ay) * t3;
        r.z = (e4.z + h4.z + az) * t3;
        r.w = (e4.w + h4.w + aw) * t3;
        *(float4*)(dst + o) = r;
    }
}

// ---- launch -------------------------------------------------------------

extern "C" void kernel_launch(void* const* d_in, const int* in_sizes, int n_in,
                              void* d_out, int out_size, void* d_ws, size_t ws_size,
                              hipStream_t stream) {
    const int* rows = (const int*)d_in[1];
    const int* cols = (const int*)d_in[2];
    const float* vals = (const float*)d_in[3];
    const float* emb = (const float*)d_in[4];
    const float* u1 = (const float*)d_in[5];
    const float* u2 = (const float*)d_in[6];
    float* out = (float*)d_out;

    const int N = in_sizes[0];
    const int E = in_sizes[1];
    const size_t ND = (size_t)N * DD;

    // workspace layout
    char* ws = (char*)d_ws;
    float* g1  = (float*)ws;  ws += ND * sizeof(float);
    float* h1  = (float*)ws;  ws += ND * sizeof(float);
    int* cnt   = (int*)ws;    ws += (size_t)N * sizeof(int);   // -> rowstart
    int* rank  = (int*)ws;    ws += (size_t)E * sizeof(int);
    Edge* ev   = (Edge*)ws;   ws += (size_t)E * sizeof(Edge);
    int* bsum  = (int*)ws;    ws += 1024 * sizeof(int);
    float* g2  = (float*)ws;  // only if ws permits a 3rd ND buffer
    bool fused = ((size_t)((char*)g2 - (char*)d_ws) + ND * sizeof(float)) <= ws_size;
    if (!fused) g2 = g1;      // reuse g1 as g2 (needs separate drop pass)

    const int total4 = (int)(ND / 4);
    const int gridElem = (total4 + 255) / 256;
    const int gridE = (E + 255) / 256;
    const int gridN = (N + 255) / 256;
    const int nScanBlocks = (N + SCAN_CHUNK - 1) / SCAN_CHUNK;
    const int gridRow = (int)(((size_t)N * 32 + 255) / 256);

    // CSR build (no float atomics anywhere)
    k_zero<<<gridN, 256, 0, stream>>>(cnt, N);
    k_hist<<<gridE, 256, 0, stream>>>(rows, cnt, rank, E);
    k_scan1<<<nScanBlocks, 256, 0, stream>>>(cnt, bsum, N);
    k_scan2<<<1, 1024, 0, stream>>>(bsum, nScanBlocks);
    k_scan3<<<gridN, 256, 0, stream>>>(cnt, bsum, N);
    k_scatter<<<gridE, 256, 0, stream>>>(rows, cols, vals, cnt, rank, ev, E);

    // layer 1: g1 = dropout(emb,u1)
    k_drop<<<gridElem, 256, 0, stream>>>(emb, u1, g1, total4);

    if (fused) {
        // h1 = A*g1; g2 = dropout(h1,u2) fused
        k_gather<1><<<gridRow, 256, 0, stream>>>(cnt, ev, g1, u2, nullptr, nullptr, h1, g2, N, E);
    } else {
        k_gather<0><<<gridRow, 256, 0, stream>>>(cnt, ev, g1, nullptr, nullptr, nullptr, h1, nullptr, N, E);
        k_drop<<<gridElem, 256, 0, stream>>>(h1, u2, g2, total4);
    }

    // layer 2: out = (emb + h1 + A*g2)/3
    k_gather<2><<<gridRow, 256, 0, stream>>>(cnt, ev, g2, nullptr, emb, h1, out, nullptr, N, E);
}

// Round 4
// 452.756 us; speedup vs baseline: 12.2468x; 1.2253x over previous
//
#include <hip/hip_runtime.h>

#define DD 128            // emb dim, fixed by problem
#define SCAN_CHUNK 1024   // elements per scan1 block

struct __align__(8) Edge { int c; float v; };

// bf16 helpers (RNE pack, cheap unpack)
__device__ __forceinline__ unsigned short f2bf(float f) {
    unsigned int u = __float_as_uint(f);
    u = u + 0x7fffu + ((u >> 16) & 1u);
    return (unsigned short)(u >> 16);
}
__device__ __forceinline__ float bf_lo(unsigned int p) { return __uint_as_float(p << 16); }
__device__ __forceinline__ float bf_hi(unsigned int p) { return __uint_as_float(p & 0xffff0000u); }

// ---- CSR build ----------------------------------------------------------

__global__ __launch_bounds__(256) void k_zero(int* __restrict__ p, int n) {
    int i = blockIdx.x * 256 + threadIdx.x;
    if (i < n) p[i] = 0;
}

__global__ __launch_bounds__(256) void k_hist(const int* __restrict__ rows,
                                              int* __restrict__ cnt,
                                              int* __restrict__ rank, int E) {
    int e = blockIdx.x * 256 + threadIdx.x;
    if (e < E) rank[e] = atomicAdd(&cnt[rows[e]], 1);
}

// per-block exclusive scan of 1024 elements (4/thread), block totals -> bsum
__global__ __launch_bounds__(256) void k_scan1(int* __restrict__ data,
                                               int* __restrict__ bsum, int n) {
    __shared__ int s[256];
    int tid = threadIdx.x;
    int base = blockIdx.x * SCAN_CHUNK + tid * 4;
    int v0 = 0, v1 = 0, v2 = 0, v3 = 0;
    if (base + 0 < n) v0 = data[base + 0];
    if (base + 1 < n) v1 = data[base + 1];
    if (base + 2 < n) v2 = data[base + 2];
    if (base + 3 < n) v3 = data[base + 3];
    int tsum = v0 + v1 + v2 + v3;
    s[tid] = tsum;
    __syncthreads();
    for (int off = 1; off < 256; off <<= 1) {
        int t = (tid >= off) ? s[tid - off] : 0;
        __syncthreads();
        s[tid] += t;
        __syncthreads();
    }
    int excl = s[tid] - tsum;
    if (tid == 255) bsum[blockIdx.x] = s[255];
    if (base + 0 < n) data[base + 0] = excl;
    if (base + 1 < n) data[base + 1] = excl + v0;
    if (base + 2 < n) data[base + 2] = excl + v0 + v1;
    if (base + 3 < n) data[base + 3] = excl + v0 + v1 + v2;
}

// fused scan2+scan3: each block serially prefixes bsum (nb<=1024) in LDS,
// then adds the proper block offset to its 256 elements.
__global__ __launch_bounds__(256) void k_scan23(int* __restrict__ data,
                                                const int* __restrict__ bsum,
                                                int nb, int n) {
    __shared__ int s[1024];
    int tid = threadIdx.x;
    for (int i = tid; i < nb; i += 256) s[i] = bsum[i];
    __syncthreads();
    if (tid == 0) {
        int run = 0;
        for (int i = 0; i < nb; ++i) { int t = s[i]; s[i] = run; run += t; }
    }
    __syncthreads();
    int i = blockIdx.x * 256 + tid;
    if (i < n) data[i] += s[i >> 10];
}

// no atomics: pos = rowstart[r] + rank[e]; packed 8B write
__global__ __launch_bounds__(256) void k_scatter(const int* __restrict__ rows,
                                                 const int* __restrict__ cols,
                                                 const float* __restrict__ vals,
                                                 const int* __restrict__ rowstart,
                                                 const int* __restrict__ rank,
                                                 Edge* __restrict__ ev, int E) {
    int e = blockIdx.x * 256 + threadIdx.x;
    if (e >= E) return;
    int r = rows[e];
    Edge ed;
    ed.c = cols[e];
    ed.v = vals[e];
    ev[rowstart[r] + rank[e]] = ed;
}

// ---- dense ops ----------------------------------------------------------

// g(bf16) = dropout(src, u)
__global__ __launch_bounds__(256) void k_drop_bf(const float* __restrict__ src,
                                                 const float* __restrict__ u,
                                                 ushort* __restrict__ g, int total4) {
    int i = blockIdx.x * 256 + threadIdx.x;
    if (i >= total4) return;
    float4 h = ((const float4*)src)[i];
    float4 uu = ((const float4*)u)[i];
    const float s = 1.0f / 0.9f;
    ushort4 o;
    o.x = f2bf((uu.x >= 0.1f) ? h.x * s : 0.0f);
    o.y = f2bf((uu.y >= 0.1f) ? h.y * s : 0.0f);
    o.z = f2bf((uu.z >= 0.1f) ? h.z * s : 0.0f);
    o.w = f2bf((uu.w >= 0.1f) ? h.w * s : 0.0f);
    ((ushort4*)g)[i] = o;
}

// gather SpMM over bf16 src, fp32 accumulate. 32 lanes/row, 4 elems/lane (8B).
// MODE 1: h1(fp32) = A*src; g2(bf16) = dropout(h1, u2)
// MODE 2: out(fp32) = (emb + h1in + A*src) / 3
template <int MODE>
__global__ __launch_bounds__(256) void k_gather(const int* __restrict__ rowstart,
                                                const Edge* __restrict__ ev,
                                                const ushort* __restrict__ srcb,
                                                const float* __restrict__ u2,
                                                const float* __restrict__ emb,
                                                const float* __restrict__ h1in,
                                                float* __restrict__ dst,
                                                ushort* __restrict__ g2,
                                                int N, int E) {
    int t = blockIdx.x * 256 + threadIdx.x;
    int row = t >> 5;
    int lane = t & 31;
    if (row >= N) return;
    int start = rowstart[row];
    int end = (row == N - 1) ? E : rowstart[row + 1];
    const uint2* s2 = (const uint2*)srcb;  // 4 bf16 per uint2; 32 uint2 per row
    float ax = 0.f, ay = 0.f, az = 0.f, aw = 0.f;
    int e = start;
    for (; e + 4 <= end; e += 4) {
        Edge e0 = ev[e + 0];
        Edge e1 = ev[e + 1];
        Edge e2 = ev[e + 2];
        Edge e3 = ev[e + 3];
        uint2 p0 = s2[((size_t)e0.c << 5) + lane];
        uint2 p1 = s2[((size_t)e1.c << 5) + lane];
        uint2 p2 = s2[((size_t)e2.c << 5) + lane];
        uint2 p3 = s2[((size_t)e3.c << 5) + lane];
        ax = fmaf(e0.v, bf_lo(p0.x), ax); ay = fmaf(e0.v, bf_hi(p0.x), ay);
        az = fmaf(e0.v, bf_lo(p0.y), az); aw = fmaf(e0.v, bf_hi(p0.y), aw);
        ax = fmaf(e1.v, bf_lo(p1.x), ax); ay = fmaf(e1.v, bf_hi(p1.x), ay);
        az = fmaf(e1.v, bf_lo(p1.y), az); aw = fmaf(e1.v, bf_hi(p1.y), aw);
        ax = fmaf(e2.v, bf_lo(p2.x), ax); ay = fmaf(e2.v, bf_hi(p2.x), ay);
        az = fmaf(e2.v, bf_lo(p2.y), az); aw = fmaf(e2.v, bf_hi(p2.y), aw);
        ax = fmaf(e3.v, bf_lo(p3.x), ax); ay = fmaf(e3.v, bf_hi(p3.x), ay);
        az = fmaf(e3.v, bf_lo(p3.y), az); aw = fmaf(e3.v, bf_hi(p3.y), aw);
    }
    for (; e < end; ++e) {
        Edge ed = ev[e];
        uint2 p = s2[((size_t)ed.c << 5) + lane];
        ax = fmaf(ed.v, bf_lo(p.x), ax); ay = fmaf(ed.v, bf_hi(p.x), ay);
        az = fmaf(ed.v, bf_lo(p.y), az); aw = fmaf(ed.v, bf_hi(p.y), aw);
    }
    size_t o = ((size_t)row << 7) + (size_t)lane * 4;
    if (MODE == 1) {
        *(float4*)(dst + o) = make_float4(ax, ay, az, aw);   // h1 fp32
        float4 uu = *(const float4*)(u2 + o);
        const float s = 1.0f / 0.9f;
        ushort4 gg;
        gg.x = f2bf((uu.x >= 0.1f) ? ax * s : 0.0f);
        gg.y = f2bf((uu.y >= 0.1f) ? ay * s : 0.0f);
        gg.z = f2bf((uu.z >= 0.1f) ? az * s : 0.0f);
        gg.w = f2bf((uu.w >= 0.1f) ? aw * s : 0.0f);
        *(ushort4*)(g2 + o) = gg;
    } else {
        float4 e4 = *(const float4*)(emb + o);
        float4 h4 = *(const float4*)(h1in + o);
        const float t3 = 1.0f / 3.0f;
        float4 r;
        r.x = (e4.x + h4.x + ax) * t3;
        r.y = (e4.y + h4.y + ay) * t3;
        r.z = (e4.z + h4.z + az) * t3;
        r.w = (e4.w + h4.w + aw) * t3;
        *(float4*)(dst + o) = r;
    }
}

// ---- launch -------------------------------------------------------------

extern "C" void kernel_launch(void* const* d_in, const int* in_sizes, int n_in,
                              void* d_out, int out_size, void* d_ws, size_t ws_size,
                              hipStream_t stream) {
    const int* rows = (const int*)d_in[1];
    const int* cols = (const int*)d_in[2];
    const float* vals = (const float*)d_in[3];
    const float* emb = (const float*)d_in[4];
    const float* u1 = (const float*)d_in[5];
    const float* u2 = (const float*)d_in[6];
    float* out = (float*)d_out;

    const int N = in_sizes[0];
    const int E = in_sizes[1];
    const size_t ND = (size_t)N * DD;

    // workspace layout (~122 MB total)
    char* ws = (char*)d_ws;
    ushort* g1 = (ushort*)ws;  ws += ND * sizeof(ushort);          // 25.6MB
    ushort* g2 = (ushort*)ws;  ws += ND * sizeof(ushort);          // 25.6MB
    float* h1  = (float*)ws;   ws += ND * sizeof(float);           // 51.2MB
    int* cnt   = (int*)ws;     ws += (size_t)N * sizeof(int);      // -> rowstart
    int* rank  = (int*)ws;     ws += (size_t)E * sizeof(int);
    Edge* ev   = (Edge*)ws;    ws += (size_t)E * sizeof(Edge);
    int* bsum  = (int*)ws;

    const int total4 = (int)(ND / 4);
    const int gridElem = (total4 + 255) / 256;
    const int gridE = (E + 255) / 256;
    const int gridN = (N + 255) / 256;
    const int nScanBlocks = (N + SCAN_CHUNK - 1) / SCAN_CHUNK;
    const int gridRow = (int)(((size_t)N * 32 + 255) / 256);

    // CSR build (no float atomics)
    k_zero<<<gridN, 256, 0, stream>>>(cnt, N);
    k_hist<<<gridE, 256, 0, stream>>>(rows, cnt, rank, E);
    k_scan1<<<nScanBlocks, 256, 0, stream>>>(cnt, bsum, N);
    k_scan23<<<gridN, 256, 0, stream>>>(cnt, bsum, nScanBlocks, N);
    k_scatter<<<gridE, 256, 0, stream>>>(rows, cols, vals, cnt, rank, ev, E);

    // layer 1: g1 = dropout(emb,u1)  [bf16]
    k_drop_bf<<<gridElem, 256, 0, stream>>>(emb, u1, g1, total4);
    // h1 = A*g1 (fp32); g2 = dropout(h1,u2) [bf16] fused
    k_gather<1><<<gridRow, 256, 0, stream>>>(cnt, ev, g1, u2, nullptr, nullptr, h1, g2, N, E);
    // layer 2: out = (emb + h1 + A*g2)/3
    k_gather<2><<<gridRow, 256, 0, stream>>>(cnt, ev, g2, nullptr, emb, h1, out, nullptr, N, E);
}